// Round 4
// baseline (2433.000 us; speedup 1.0000x reference)
//
#include <hip/hip_runtime.h>
#include <stdint.h>

typedef unsigned short u16;
typedef __attribute__((ext_vector_type(8))) short bf16x8;
typedef __attribute__((ext_vector_type(4))) float f32x4;

#define NB 2
#define NS 2048
#define ND 1024
#define NH 16
#define NL 4
#define NV 32000
#define NF 4096
#define NDH 64
#define NM (NB*NS)   // 4096 token rows

__device__ __forceinline__ u16 f2b(float f) {
  union { float f; uint32_t u; } v; v.f = f;
  uint32_t r = v.u + 0x7FFFu + ((v.u >> 16) & 1u);
  return (u16)(r >> 16);
}

#define GLOAD_LDS16(gp, lp) __builtin_amdgcn_global_load_lds( \
    (const __attribute__((address_space(1))) void*)(gp), \
    (__attribute__((address_space(3))) void*)(lp), 16, 0, 0)

// ---------------- transpose + fp32->bf16 convert: w[K][N] -> wt[N][K] ----------------
__global__ __launch_bounds__(256)
void k_transpose_convert(const float* __restrict__ w, u16* __restrict__ wt, int K, int N) {
  __shared__ float tile[32][33];
  int n0 = blockIdx.x * 32;
  int k0 = blockIdx.y * 32;
  int tx = threadIdx.x & 31;
  int ty = threadIdx.x >> 5; // 0..7
#pragma unroll
  for (int i = 0; i < 4; i++) {
    int kk = ty + i * 8;
    tile[kk][tx] = w[(size_t)(k0 + kk) * N + (n0 + tx)];
  }
  __syncthreads();
#pragma unroll
  for (int i = 0; i < 4; i++) {
    int nn = ty + i * 8;
    wt[(size_t)(n0 + nn) * K + (k0 + tx)] = f2b(tile[tx][nn]);
  }
}

// ---------------- embedding + sinusoidal PE ----------------
__global__ __launch_bounds__(256)
void k_embed(const int* __restrict__ ids, const float* __restrict__ emb,
             float* __restrict__ x, u16* __restrict__ xb) {
  int row = blockIdx.x;          // b*NS + s
  int s = row & (NS - 1);
  int tok = ids[row];
  const float* e = emb + (size_t)tok * ND;
  int d0 = threadIdx.x * 4;
  float y[4];
#pragma unroll
  for (int j = 0; j < 4; j++) {
    int dd = d0 + j;
    float di = (float)(dd & ~1);
    float dv = expf(di * (-9.210340371976184f / (float)ND));
    float ang = (float)s * dv;
    float pe = (dd & 1) ? cosf(ang) : sinf(ang);
    y[j] = e[dd] * 32.0f + pe;
  }
  float4 w; w.x = y[0]; w.y = y[1]; w.z = y[2]; w.w = y[3];
  *(float4*)(x + (size_t)row * ND + d0) = w;
  uint2 pk;
  pk.x = (uint32_t)f2b(y[0]) | ((uint32_t)f2b(y[1]) << 16);
  pk.y = (uint32_t)f2b(y[2]) | ((uint32_t)f2b(y[3]) << 16);
  *(uint2*)(xb + (size_t)row * ND + d0) = pk;
}

// ---------------- fused residual add + LayerNorm ----------------
__global__ __launch_bounds__(256)
void k_ln(const float* __restrict__ xin, const float* __restrict__ add,
          const float* __restrict__ g, const float* __restrict__ bb,
          float* __restrict__ xout, u16* __restrict__ xbout) {
  int row = blockIdx.x;
  int t = threadIdx.x;
  const float4 xi = *(const float4*)(xin + (size_t)row * ND + t * 4);
  const float4 ai = *(const float4*)(add + (size_t)row * ND + t * 4);
  float v0 = xi.x + ai.x, v1 = xi.y + ai.y, v2 = xi.z + ai.z, v3 = xi.w + ai.w;
  float s = v0 + v1 + v2 + v3;
  float s2 = v0 * v0 + v1 * v1 + v2 * v2 + v3 * v3;
#pragma unroll
  for (int d = 32; d >= 1; d >>= 1) { s += __shfl_xor(s, d); s2 += __shfl_xor(s2, d); }
  __shared__ float rs[8];
  int w = t >> 6;
  if ((t & 63) == 0) { rs[w] = s; rs[4 + w] = s2; }
  __syncthreads();
  s = rs[0] + rs[1] + rs[2] + rs[3];
  s2 = rs[4] + rs[5] + rs[6] + rs[7];
  float mu = s * (1.0f / ND);
  float var = s2 * (1.0f / ND) - mu * mu;
  float rr = rsqrtf(var + 1e-5f);
  const float4 gg = *(const float4*)(g + t * 4);
  const float4 be = *(const float4*)(bb + t * 4);
  float y0 = (v0 - mu) * rr * gg.x + be.x;
  float y1 = (v1 - mu) * rr * gg.y + be.y;
  float y2 = (v2 - mu) * rr * gg.z + be.z;
  float y3 = (v3 - mu) * rr * gg.w + be.w;
  float4 yo; yo.x = y0; yo.y = y1; yo.z = y2; yo.w = y3;
  *(float4*)(xout + (size_t)row * ND + t * 4) = yo;
  uint2 pk;
  pk.x = (uint32_t)f2b(y0) | ((uint32_t)f2b(y1) << 16);
  pk.y = (uint32_t)f2b(y2) | ((uint32_t)f2b(y3) << 16);
  *(uint2*)(xbout + (size_t)row * ND + t * 4) = pk;
}

// ---------------- bf16 MFMA GEMM: C[M][N] = A[M][K] @ Bt[N][K]^T + bias ----------------
// global_load_lds staging (m97 structure), plain M-fastest grid (round-1 measured-good).
// MODE 0: fp32 store to Cf
// MODE 1: relu, bf16 store to Cb
// MODE 3: fused QKV: N=3072, scale q; Q,K -> [B,H,S,DH]; V -> [B,H,DH,S] (transposed)
template<int MODE>
__global__ __launch_bounds__(256)
void k_gemm_bt(const u16* __restrict__ A, const u16* __restrict__ Bt,
               const float* __restrict__ bias0, const float* __restrict__ bias1,
               const float* __restrict__ bias2,
               float* __restrict__ Cf, u16* __restrict__ Cb,
               int M, int N, int K, float scale) {
  constexpr int BM = 128, BN = 128, BK = 32;
  __shared__ __align__(16) u16 As[2][BM * BK];
  __shared__ __align__(16) u16 Bs[2][BN * BK];

  const int tid = threadIdx.x;
  const int lane = tid & 63;
  const int wave = tid >> 6;

  const int bm = blockIdx.x * BM;
  const int bn = blockIdx.y * BN;

  const int wr = (wave >> 1) * 64;
  const int wc = (wave & 1) * 64;
  const int lr = lane & 15;
  const int lk = (lane >> 4) * 8;

  const u16* Abase = A + (size_t)bm * K;
  const u16* Bbase = Bt + (size_t)bn * K;
  const int srow = lane >> 2;        // 0..15
  const int scol = (lane & 3) * 8;   // u16 col within BK

  auto stage = [&](int buf, int kt) {
    const u16* Ag = Abase + (size_t)kt * BK + scol;
    const u16* Bg = Bbase + (size_t)kt * BK + scol;
#pragma unroll
    for (int i = 0; i < 2; i++) {
      const int rbase = (i * 4 + wave) * 16;       // first row of this 1KB chunk
      GLOAD_LDS16(Ag + (size_t)(rbase + srow) * K, &As[buf][rbase * BK]);
      GLOAD_LDS16(Bg + (size_t)(rbase + srow) * K, &Bs[buf][rbase * BK]);
    }
  };

  f32x4 acc[4][4] = {};
  const int nk = K / BK;
  stage(0, 0);
  for (int kt = 0; kt < nk; ++kt) {
    __syncthreads();                       // drains vmcnt -> buf[kt&1] ready
    if (kt + 1 < nk) stage((kt + 1) & 1, kt + 1);
    const int buf = kt & 1;
    bf16x8 af[4], bfv[4];
#pragma unroll
    for (int m = 0; m < 4; m++)
      af[m] = *(const bf16x8*)(&As[buf][(wr + m * 16 + lr) * BK + lk]);
#pragma unroll
    for (int n = 0; n < 4; n++)
      bfv[n] = *(const bf16x8*)(&Bs[buf][(wc + n * 16 + lr) * BK + lk]);
#pragma unroll
    for (int m = 0; m < 4; m++)
#pragma unroll
      for (int n = 0; n < 4; n++)
        acc[m][n] = __builtin_amdgcn_mfma_f32_16x16x32_bf16(af[m], bfv[n], acc[m][n], 0, 0, 0);
  }

  const int lg = lane >> 4;
#pragma unroll
  for (int m = 0; m < 4; m++) {
#pragma unroll
    for (int n = 0; n < 4; n++) {
      int col = bn + wc + n * 16 + lr;
      float bv;
      if (MODE == 3) {
        int which = col >> 10;
        int cc = col & 1023;
        const float* bp = (which == 0) ? bias0 : ((which == 1) ? bias1 : bias2);
        bv = bp[cc];
      } else {
        bv = bias0[col];
      }
      if (MODE == 3 && (col >> 10) == 2) {
        // V: packed transposed store -> [B,H,DH,S]
        int cc = col & 1023;
        int row0 = bm + wr + m * 16 + lg * 4;
        int b_ = row0 >> 11;
        int s_ = row0 & (NS - 1);
        int h_ = cc >> 6;
        int dh = cc & 63;
        ushort4 pk;
        pk.x = f2b(acc[m][n][0] + bv);
        pk.y = f2b(acc[m][n][1] + bv);
        pk.z = f2b(acc[m][n][2] + bv);
        pk.w = f2b(acc[m][n][3] + bv);
        *(ushort4*)(Cb + (size_t)2 * NM * ND +
                    ((((size_t)b_ * NH + h_) * NDH) + dh) * NS + s_) = pk;
        continue;
      }
#pragma unroll
      for (int j = 0; j < 4; j++) {
        int row = bm + wr + m * 16 + lg * 4 + j;
        float v = acc[m][n][j] + bv;
        if (MODE == 0) {
          Cf[(size_t)row * N + col] = v;
        } else if (MODE == 1) {
          Cb[(size_t)row * N + col] = f2b(fmaxf(v, 0.0f));
        } else { // MODE 3: Q/K permuted store -> [B,H,S,DH]
          int which = col >> 10;
          int cc = col & 1023;
          if (which == 0) v *= scale;
          int b_ = row >> 11;          // /NS
          int s_ = row & (NS - 1);
          int h_ = cc >> 6;
          int dh = cc & 63;
          Cb[(size_t)which * ((size_t)NM * ND) +
             ((((size_t)b_ * NH + h_) * NS) + s_) * NDH + dh] = f2b(v);
        }
      }
    }
  }
}

// ---------------- flash attention (causal), Q pre-scaled by 1/sqrt(DH) ----------------
// Q,K: [B,H,S,DH] bf16.  V: [B,H,DH,S] bf16 (pre-transposed).  O: [B,S,H*DH] bf16.
// K/V fragments read DIRECTLY from global (L2-resident, 256KB per bh) — no K/V LDS,
// no barriers (Common-mistake #7 / m169). P kept in per-wave swizzled LDS.
__global__ __launch_bounds__(256)
void k_attn(const u16* __restrict__ Q, const u16* __restrict__ Kq,
            const u16* __restrict__ Vt, u16* __restrict__ O) {
  const int qt = blockIdx.x;   // q tile of 64 rows
  const int bh = blockIdx.y;   // b*NH + h
  const int b_ = bh >> 4, h_ = bh & 15;
  const int tid = threadIdx.x, lane = tid & 63, wave = tid >> 6;
  const int lr = lane & 15, lg = lane >> 4;

  __shared__ __align__(16) u16 Ps[4][16 * 64];   // per-wave P [qrow][key] swizzled

  const size_t base = (size_t)bh * NS * NDH;     // same for [B,H,S,DH] and [B,H,DH,S]
  bf16x8 qf0, qf1;
  {
    const u16* qp = Q + base + (size_t)(qt * 64 + wave * 16 + lr) * NDH;
    qf0 = *(const bf16x8*)(qp + lg * 8);
    qf1 = *(const bf16x8*)(qp + 32 + lg * 8);
  }

  float mrun[4] = {-1e30f, -1e30f, -1e30f, -1e30f};
  float lrun[4] = {0.f, 0.f, 0.f, 0.f};
  f32x4 oacc[4] = {};
  const int q0 = qt * 64 + wave * 16;

  for (int kt2 = 0; kt2 <= qt; ++kt2) {
    const u16* Kg = Kq + base + (size_t)(kt2 * 64) * NDH;
    const u16* Vg = Vt + base + kt2 * 64;        // row d stride NS

    f32x4 sc[4];
#pragma unroll
    for (int c = 0; c < 4; c++) {
      const u16* kp = Kg + (size_t)(c * 16 + lr) * NDH + lg * 8;
      bf16x8 k0 = *(const bf16x8*)(kp);
      bf16x8 k1 = *(const bf16x8*)(kp + 32);
      f32x4 s = {};
      s = __builtin_amdgcn_mfma_f32_16x16x32_bf16(qf0, k0, s, 0, 0, 0);
      s = __builtin_amdgcn_mfma_f32_16x16x32_bf16(qf1, k1, s, 0, 0, 0);
      sc[c] = s;
    }

    if (kt2 == qt) {  // diagonal tile: causal mask
#pragma unroll
      for (int c = 0; c < 4; c++)
#pragma unroll
        for (int j = 0; j < 4; j++) {
          int qg = q0 + lg * 4 + j;
          int kg = qt * 64 + c * 16 + lr;
          if (kg > qg) sc[c][j] = -1e9f;
        }
    }

#pragma unroll
    for (int j = 0; j < 4; j++) {
      float mt = fmaxf(fmaxf(sc[0][j], sc[1][j]), fmaxf(sc[2][j], sc[3][j]));
#pragma unroll
      for (int d = 8; d >= 1; d >>= 1) mt = fmaxf(mt, __shfl_xor(mt, d));
      float mnew = fmaxf(mrun[j], mt);
      float corr = __expf(mrun[j] - mnew);
      float ps = 0.f;
#pragma unroll
      for (int c = 0; c < 4; c++) {
        float p = __expf(sc[c][j] - mnew);
        sc[c][j] = p;
        ps += p;
      }
#pragma unroll
      for (int d = 8; d >= 1; d >>= 1) ps += __shfl_xor(ps, d);
      lrun[j] = lrun[j] * corr + ps;
      mrun[j] = mnew;
#pragma unroll
      for (int n = 0; n < 4; n++) oacc[n][j] *= corr;
    }

    char* pw = (char*)Ps[wave];
#pragma unroll
    for (int c = 0; c < 4; c++)
#pragma unroll
      for (int j = 0; j < 4; j++) {
        int row = lg * 4 + j;
        *(u16*)(pw + row * 128 + ((((c * 16 + lr) * 2)) ^ ((row & 7) << 4))) = f2b(sc[c][j]);
      }

    {
      int smq = (lr & 7) << 4;
      bf16x8 pa0 = *(const bf16x8*)(pw + lr * 128 + ((lg * 16) ^ smq));
      bf16x8 pa1 = *(const bf16x8*)(pw + lr * 128 + ((64 + lg * 16) ^ smq));
#pragma unroll
      for (int n = 0; n < 4; n++) {
        const u16* vp = Vg + (size_t)(n * 16 + lr) * NS + lg * 8;
        bf16x8 v0 = *(const bf16x8*)(vp);
        bf16x8 v1 = *(const bf16x8*)(vp + 32);
        oacc[n] = __builtin_amdgcn_mfma_f32_16x16x32_bf16(pa0, v0, oacc[n], 0, 0, 0);
        oacc[n] = __builtin_amdgcn_mfma_f32_16x16x32_bf16(pa1, v1, oacc[n], 0, 0, 0);
      }
    }
  }

#pragma unroll
  for (int j = 0; j < 4; j++) {
    float inv = 1.0f / lrun[j];
    int s_ = qt * 64 + wave * 16 + lg * 4 + j;
    size_t orow = ((size_t)b_ * NS + s_) * ND + h_ * NDH;
#pragma unroll
    for (int n = 0; n < 4; n++)
      O[orow + n * 16 + lr] = f2b(oacc[n][j] * inv);
  }
}

// ---------------- host launch ----------------
extern "C" void kernel_launch(void* const* d_in, const int* in_sizes, int n_in,
                              void* d_out, int out_size, void* d_ws, size_t ws_size,
                              hipStream_t stream) {
  const int* ids = (const int*)d_in[0];
  const float* tok_emb = (const float*)d_in[1];
  const float* Wq = (const float*)d_in[2];
  const float* bq = (const float*)d_in[3];
  const float* Wk = (const float*)d_in[4];
  const float* bk = (const float*)d_in[5];
  const float* Wv = (const float*)d_in[6];
  const float* bv = (const float*)d_in[7];
  const float* Wo = (const float*)d_in[8];
  const float* bo = (const float*)d_in[9];
  const float* ln1g = (const float*)d_in[10];
  const float* ln1b = (const float*)d_in[11];
  const float* W1 = (const float*)d_in[12];
  const float* b1 = (const float*)d_in[13];
  const float* W2 = (const float*)d_in[14];
  const float* b2 = (const float*)d_in[15];
  const float* ln3g = (const float*)d_in[16];
  const float* ln3b = (const float*)d_in[17];
  const float* Wout = (const float*)d_in[18];
  const float* bout = (const float*)d_in[19];
  float* out = (float*)d_out;

  char* ws = (char*)d_ws;
  size_t off = 0;
  auto alloc = [&](size_t bytes) -> void* {
    void* p = ws + off;
    off += (bytes + 255) & ~(size_t)255;
    return p;
  };
  float* x    = (float*)alloc((size_t)NM * ND * 4);
  float* tmp  = (float*)alloc((size_t)NM * ND * 4);
  u16* xb     = (u16*)alloc((size_t)NM * ND * 2);
  u16* hb     = (u16*)alloc((size_t)NM * NF * 2);
  u16* qkvb   = (u16*)alloc((size_t)3 * NM * ND * 2);   // Q,K:[B,H,S,DH]; V:[B,H,DH,S]
  u16* ob     = (u16*)alloc((size_t)NM * ND * 2);
  u16* Wqkvt  = (u16*)alloc((size_t)NL * 3 * ND * ND * 2); // [L][3072][1024]
  u16* Wot    = (u16*)alloc((size_t)NL * ND * ND * 2);
  u16* W1t    = (u16*)alloc((size_t)NL * (size_t)NF * ND * 2);
  u16* W2t    = (u16*)alloc((size_t)NL * (size_t)ND * NF * 2);
  u16* Woutt  = (u16*)alloc((size_t)NV * ND * 2);

  // ---- weight transpose+convert (every call; deterministic) ----
  for (int l = 0; l < NL; l++) {
    size_t wl = (size_t)l * ND * ND;
    u16* qkvl = Wqkvt + (size_t)l * 3 * ND * ND;
    dim3 gdd(ND / 32, ND / 32);
    k_transpose_convert<<<gdd, 256, 0, stream>>>(Wq + wl, qkvl, ND, ND);
    k_transpose_convert<<<gdd, 256, 0, stream>>>(Wk + wl, qkvl + (size_t)ND * ND, ND, ND);
    k_transpose_convert<<<gdd, 256, 0, stream>>>(Wv + wl, qkvl + (size_t)2 * ND * ND, ND, ND);
    k_transpose_convert<<<gdd, 256, 0, stream>>>(Wo + wl, Wot + wl, ND, ND);
    k_transpose_convert<<<dim3(NF / 32, ND / 32), 256, 0, stream>>>(
        W1 + (size_t)l * ND * NF, W1t + (size_t)l * (size_t)NF * ND, ND, NF);
    k_transpose_convert<<<dim3(ND / 32, NF / 32), 256, 0, stream>>>(
        W2 + (size_t)l * NF * ND, W2t + (size_t)l * (size_t)ND * NF, NF, ND);
  }
  k_transpose_convert<<<dim3(NV / 32, ND / 32), 256, 0, stream>>>(Wout, Woutt, ND, NV);

  // ---- embed + PE ----
  k_embed<<<NM, 256, 0, stream>>>(ids, tok_emb, x, xb);

  for (int l = 0; l < NL; l++) {
    size_t wl = (size_t)l * ND * ND;
    u16* qkvl = Wqkvt + (size_t)l * 3 * ND * ND;

    // fused QKV: [4096,1024] @ [1024,3072]; Q scaled 0.125; V stored transposed
    k_gemm_bt<3><<<dim3(NM / 128, 3 * ND / 128), 256, 0, stream>>>(
        xb, qkvl, bq + l * ND, bk + l * ND, bv + l * ND,
        nullptr, qkvb, NM, 3 * ND, ND, 0.125f);

    // flash attention
    k_attn<<<dim3(NS / 64, NB * NH), 256, 0, stream>>>(
        qkvb, qkvb + (size_t)NM * ND, qkvb + (size_t)2 * NM * ND, ob);

    // O projection (fp32 out)
    k_gemm_bt<0><<<dim3(NM / 128, ND / 128), 256, 0, stream>>>(
        ob, Wot + wl, bo + l * ND, nullptr, nullptr, tmp, nullptr, NM, ND, ND, 1.0f);

    // x = LN(x + attn_out)
    k_ln<<<NM, 256, 0, stream>>>(x, tmp, ln1g + l * ND, ln1b + l * ND, x, xb);

    // FFN1: relu, bf16 out
    k_gemm_bt<1><<<dim3(NM / 128, NF / 128), 256, 0, stream>>>(
        xb, W1t + (size_t)l * (size_t)NF * ND, b1 + l * NF, nullptr, nullptr,
        nullptr, hb, NM, NF, ND, 1.0f);

    // FFN2: fp32 out
    k_gemm_bt<0><<<dim3(NM / 128, ND / 128), 256, 0, stream>>>(
        hb, W2t + (size_t)l * (size_t)ND * NF, b2 + l * ND, nullptr, nullptr,
        tmp, nullptr, NM, ND, NF, 1.0f);

    // x = LN(x + ffn_out)
    k_ln<<<NM, 256, 0, stream>>>(x, tmp, ln3g + l * ND, ln3b + l * ND, x, xb);
  }

  // ---- logits: [4096,1024] @ [1024,32000] -> d_out fp32, M-fastest grid ----
  k_gemm_bt<0><<<dim3(NM / 128, NV / 128), 256, 0, stream>>>(
      xb, Woutt, bout, nullptr, nullptr, out, nullptr, NM, NV, ND, 1.0f);
}

// Round 5
// 1993.192 us; speedup vs baseline: 1.2207x; 1.2207x over previous
//
#include <hip/hip_runtime.h>
#include <stdint.h>

typedef unsigned short u16;
typedef __attribute__((ext_vector_type(8))) short bf16x8;
typedef __attribute__((ext_vector_type(4))) float f32x4;

#define NB 2
#define NS 2048
#define ND 1024
#define NH 16
#define NL 4
#define NV 32000
#define NF 4096
#define NDH 64
#define NM (NB*NS)   // 4096 token rows

__device__ __forceinline__ u16 f2b(float f) {
  union { float f; uint32_t u; } v; v.f = f;
  uint32_t r = v.u + 0x7FFFu + ((v.u >> 16) & 1u);
  return (u16)(r >> 16);
}

#define GLOAD_LDS16(gp, lp) __builtin_amdgcn_global_load_lds( \
    (const __attribute__((address_space(1))) void*)(gp), \
    (__attribute__((address_space(3))) void*)(lp), 16, 0, 0)

// ---------------- transpose + fp32->bf16 convert: w[K][N] -> wt[N][K] ----------------
__global__ __launch_bounds__(256)
void k_transpose_convert(const float* __restrict__ w, u16* __restrict__ wt, int K, int N) {
  __shared__ float tile[32][33];
  int n0 = blockIdx.x * 32;
  int k0 = blockIdx.y * 32;
  int tx = threadIdx.x & 31;
  int ty = threadIdx.x >> 5; // 0..7
#pragma unroll
  for (int i = 0; i < 4; i++) {
    int kk = ty + i * 8;
    tile[kk][tx] = w[(size_t)(k0 + kk) * N + (n0 + tx)];
  }
  __syncthreads();
#pragma unroll
  for (int i = 0; i < 4; i++) {
    int nn = ty + i * 8;
    wt[(size_t)(n0 + nn) * K + (k0 + tx)] = f2b(tile[tx][nn]);
  }
}

// ---------------- embedding + sinusoidal PE ----------------
__global__ __launch_bounds__(256)
void k_embed(const int* __restrict__ ids, const float* __restrict__ emb,
             float* __restrict__ x, u16* __restrict__ xb) {
  int row = blockIdx.x;          // b*NS + s
  int s = row & (NS - 1);
  int tok = ids[row];
  const float* e = emb + (size_t)tok * ND;
  int d0 = threadIdx.x * 4;
  float y[4];
#pragma unroll
  for (int j = 0; j < 4; j++) {
    int dd = d0 + j;
    float di = (float)(dd & ~1);
    float dv = expf(di * (-9.210340371976184f / (float)ND));
    float ang = (float)s * dv;
    float pe = (dd & 1) ? cosf(ang) : sinf(ang);
    y[j] = e[dd] * 32.0f + pe;
  }
  float4 w; w.x = y[0]; w.y = y[1]; w.z = y[2]; w.w = y[3];
  *(float4*)(x + (size_t)row * ND + d0) = w;
  uint2 pk;
  pk.x = (uint32_t)f2b(y[0]) | ((uint32_t)f2b(y[1]) << 16);
  pk.y = (uint32_t)f2b(y[2]) | ((uint32_t)f2b(y[3]) << 16);
  *(uint2*)(xb + (size_t)row * ND + d0) = pk;
}

// ---------------- fused residual add + LayerNorm ----------------
__global__ __launch_bounds__(256)
void k_ln(const float* __restrict__ xin, const float* __restrict__ add,
          const float* __restrict__ g, const float* __restrict__ bb,
          float* __restrict__ xout, u16* __restrict__ xbout) {
  int row = blockIdx.x;
  int t = threadIdx.x;
  const float4 xi = *(const float4*)(xin + (size_t)row * ND + t * 4);
  const float4 ai = *(const float4*)(add + (size_t)row * ND + t * 4);
  float v0 = xi.x + ai.x, v1 = xi.y + ai.y, v2 = xi.z + ai.z, v3 = xi.w + ai.w;
  float s = v0 + v1 + v2 + v3;
  float s2 = v0 * v0 + v1 * v1 + v2 * v2 + v3 * v3;
#pragma unroll
  for (int d = 32; d >= 1; d >>= 1) { s += __shfl_xor(s, d); s2 += __shfl_xor(s2, d); }
  __shared__ float rs[8];
  int w = t >> 6;
  if ((t & 63) == 0) { rs[w] = s; rs[4 + w] = s2; }
  __syncthreads();
  s = rs[0] + rs[1] + rs[2] + rs[3];
  s2 = rs[4] + rs[5] + rs[6] + rs[7];
  float mu = s * (1.0f / ND);
  float var = s2 * (1.0f / ND) - mu * mu;
  float rr = rsqrtf(var + 1e-5f);
  const float4 gg = *(const float4*)(g + t * 4);
  const float4 be = *(const float4*)(bb + t * 4);
  float y0 = (v0 - mu) * rr * gg.x + be.x;
  float y1 = (v1 - mu) * rr * gg.y + be.y;
  float y2 = (v2 - mu) * rr * gg.z + be.z;
  float y3 = (v3 - mu) * rr * gg.w + be.w;
  float4 yo; yo.x = y0; yo.y = y1; yo.z = y2; yo.w = y3;
  *(float4*)(xout + (size_t)row * ND + t * 4) = yo;
  uint2 pk;
  pk.x = (uint32_t)f2b(y0) | ((uint32_t)f2b(y1) << 16);
  pk.y = (uint32_t)f2b(y2) | ((uint32_t)f2b(y3) << 16);
  *(uint2*)(xbout + (size_t)row * ND + t * 4) = pk;
}

// ---------------- bf16 MFMA GEMM: C[M][N] = A[M][K] @ Bt[N][K]^T + bias ----------------
// global_load_lds staging (m97 structure), plain M-fastest grid (measured-good).
// MODE 0: fp32 store to Cf
// MODE 1: relu, bf16 store to Cb
// MODE 3: fused QKV: N=3072, scale q; Q,K -> [B,H,S,DH]; V -> [B,H,DH,S] (transposed)
template<int MODE>
__global__ __launch_bounds__(256)
void k_gemm_bt(const u16* __restrict__ A, const u16* __restrict__ Bt,
               const float* __restrict__ bias0, const float* __restrict__ bias1,
               const float* __restrict__ bias2,
               float* __restrict__ Cf, u16* __restrict__ Cb,
               int M, int N, int K, float scale) {
  constexpr int BM = 128, BN = 128, BK = 32;
  __shared__ __align__(16) u16 As[2][BM * BK];
  __shared__ __align__(16) u16 Bs[2][BN * BK];

  const int tid = threadIdx.x;
  const int lane = tid & 63;
  const int wave = tid >> 6;

  const int bm = blockIdx.x * BM;
  const int bn = blockIdx.y * BN;

  const int wr = (wave >> 1) * 64;
  const int wc = (wave & 1) * 64;
  const int lr = lane & 15;
  const int lk = (lane >> 4) * 8;

  const u16* Abase = A + (size_t)bm * K;
  const u16* Bbase = Bt + (size_t)bn * K;
  const int srow = lane >> 2;        // 0..15
  const int scol = (lane & 3) * 8;   // u16 col within BK

  auto stage = [&](int buf, int kt) {
    const u16* Ag = Abase + (size_t)kt * BK + scol;
    const u16* Bg = Bbase + (size_t)kt * BK + scol;
#pragma unroll
    for (int i = 0; i < 2; i++) {
      const int rbase = (i * 4 + wave) * 16;       // first row of this 1KB chunk
      GLOAD_LDS16(Ag + (size_t)(rbase + srow) * K, &As[buf][rbase * BK]);
      GLOAD_LDS16(Bg + (size_t)(rbase + srow) * K, &Bs[buf][rbase * BK]);
    }
  };

  f32x4 acc[4][4] = {};
  const int nk = K / BK;
  stage(0, 0);
  for (int kt = 0; kt < nk; ++kt) {
    __syncthreads();                       // drains vmcnt -> buf[kt&1] ready
    if (kt + 1 < nk) stage((kt + 1) & 1, kt + 1);
    const int buf = kt & 1;
    bf16x8 af[4], bfv[4];
#pragma unroll
    for (int m = 0; m < 4; m++)
      af[m] = *(const bf16x8*)(&As[buf][(wr + m * 16 + lr) * BK + lk]);
#pragma unroll
    for (int n = 0; n < 4; n++)
      bfv[n] = *(const bf16x8*)(&Bs[buf][(wc + n * 16 + lr) * BK + lk]);
#pragma unroll
    for (int m = 0; m < 4; m++)
#pragma unroll
      for (int n = 0; n < 4; n++)
        acc[m][n] = __builtin_amdgcn_mfma_f32_16x16x32_bf16(af[m], bfv[n], acc[m][n], 0, 0, 0);
  }

  const int lg = lane >> 4;
#pragma unroll
  for (int m = 0; m < 4; m++) {
#pragma unroll
    for (int n = 0; n < 4; n++) {
      int col = bn + wc + n * 16 + lr;
      float bv;
      if (MODE == 3) {
        int which = col >> 10;
        int cc = col & 1023;
        const float* bp = (which == 0) ? bias0 : ((which == 1) ? bias1 : bias2);
        bv = bp[cc];
      } else {
        bv = bias0[col];
      }
      if (MODE == 3 && (col >> 10) == 2) {
        // V: packed transposed store -> [B,H,DH,S]
        int cc = col & 1023;
        int row0 = bm + wr + m * 16 + lg * 4;
        int b_ = row0 >> 11;
        int s_ = row0 & (NS - 1);
        int h_ = cc >> 6;
        int dh = cc & 63;
        ushort4 pk;
        pk.x = f2b(acc[m][n][0] + bv);
        pk.y = f2b(acc[m][n][1] + bv);
        pk.z = f2b(acc[m][n][2] + bv);
        pk.w = f2b(acc[m][n][3] + bv);
        *(ushort4*)(Cb + (size_t)2 * NM * ND +
                    ((((size_t)b_ * NH + h_) * NDH) + dh) * NS + s_) = pk;
        continue;
      }
#pragma unroll
      for (int j = 0; j < 4; j++) {
        int row = bm + wr + m * 16 + lg * 4 + j;
        float v = acc[m][n][j] + bv;
        if (MODE == 0) {
          Cf[(size_t)row * N + col] = v;
        } else if (MODE == 1) {
          Cb[(size_t)row * N + col] = f2b(fmaxf(v, 0.0f));
        } else { // MODE 3: Q/K permuted store -> [B,H,S,DH]
          int which = col >> 10;
          int cc = col & 1023;
          if (which == 0) v *= scale;
          int b_ = row >> 11;          // /NS
          int s_ = row & (NS - 1);
          int h_ = cc >> 6;
          int dh = cc & 63;
          Cb[(size_t)which * ((size_t)NM * ND) +
             ((((size_t)b_ * NH + h_) * NS) + s_) * NDH + dh] = f2b(v);
        }
      }
    }
  }
}

// ---------------- flash attention (causal), Q pre-scaled by 1/sqrt(DH) ----------------
// Q,K: [B,H,S,DH] bf16.  V: [B,H,DH,S] bf16 (pre-transposed).  O: [B,S,H*DH] bf16.
// Round-3 staged+swizzled structure + T14 async-STAGE (reg prefetch of next tile
// under compute) + T5 setprio around MFMA clusters.
__global__ __launch_bounds__(256)
void k_attn(const u16* __restrict__ Q, const u16* __restrict__ Kq,
            const u16* __restrict__ Vt, u16* __restrict__ O) {
  const int qt = blockIdx.x;   // q tile of 64 rows
  const int bh = blockIdx.y;   // b*NH + h
  const int b_ = bh >> 4, h_ = bh & 15;
  const int tid = threadIdx.x, lane = tid & 63, wave = tid >> 6;
  const int lr = lane & 15, lg = lane >> 4;

  __shared__ __align__(16) u16 Ks[64 * 64];      // [key][dh] swizzled
  __shared__ __align__(16) u16 Vs[64 * 64];      // [dh][key] swizzled
  __shared__ __align__(16) u16 Ps[4][16 * 64];   // per-wave P [qrow][key] swizzled

  const size_t base = (size_t)bh * NS * NDH;     // same for [B,H,S,DH] and [B,H,DH,S]
  bf16x8 qf0, qf1;
  {
    const u16* qp = Q + base + (size_t)(qt * 64 + wave * 16 + lr) * NDH;
    qf0 = *(const bf16x8*)(qp + lg * 8);
    qf1 = *(const bf16x8*)(qp + 32 + lg * 8);
  }

  // staging geometry (fixed per thread)
  const int idx0 = tid, idx1 = tid + 256;
  const int r0 = idx0 >> 3, r1 = idx1 >> 3;          // row 0..63
  const int c0 = (idx0 & 7) * 8, c1 = (idx1 & 7) * 8; // u16 col
  const int so0 = r0 * 128 + ((c0 * 2) ^ ((r0 & 7) << 4));
  const int so1 = r1 * 128 + ((c1 * 2) ^ ((r1 & 7) << 4));

  bf16x8 rk0, rk1, rv0, rv1;   // T14 prefetch registers
  auto loadregs = [&](int kt2) {
    const u16* Kg = Kq + base + (size_t)(kt2 * 64) * NDH;
    const u16* Vg = Vt + base + kt2 * 64;            // row d stride NS
    rk0 = *(const bf16x8*)(Kg + (size_t)r0 * NDH + c0);
    rk1 = *(const bf16x8*)(Kg + (size_t)r1 * NDH + c1);
    rv0 = *(const bf16x8*)(Vg + (size_t)r0 * NS + c0);
    rv1 = *(const bf16x8*)(Vg + (size_t)r1 * NS + c1);
  };

  float mrun[4] = {-1e30f, -1e30f, -1e30f, -1e30f};
  float lrun[4] = {0.f, 0.f, 0.f, 0.f};
  f32x4 oacc[4] = {};
  const int q0 = qt * 64 + wave * 16;

  loadregs(0);
  for (int kt2 = 0; kt2 <= qt; ++kt2) {
    // write prefetched tile to LDS
    *(bf16x8*)((char*)Ks + so0) = rk0;
    *(bf16x8*)((char*)Ks + so1) = rk1;
    *(bf16x8*)((char*)Vs + so0) = rv0;
    *(bf16x8*)((char*)Vs + so1) = rv1;
    __syncthreads();
    if (kt2 < qt) loadregs(kt2 + 1);   // T14: issue next-tile loads under compute

    f32x4 sc[4];
    __builtin_amdgcn_s_setprio(1);
#pragma unroll
    for (int c = 0; c < 4; c++) {
      int row = c * 16 + lr;
      const char* kp = (const char*)Ks + row * 128;
      int sm = (row & 7) << 4;
      bf16x8 k0 = *(const bf16x8*)(kp + ((lg * 16) ^ sm));
      bf16x8 k1 = *(const bf16x8*)(kp + ((64 + lg * 16) ^ sm));
      f32x4 s = {};
      s = __builtin_amdgcn_mfma_f32_16x16x32_bf16(qf0, k0, s, 0, 0, 0);
      s = __builtin_amdgcn_mfma_f32_16x16x32_bf16(qf1, k1, s, 0, 0, 0);
      sc[c] = s;
    }
    __builtin_amdgcn_s_setprio(0);

    if (kt2 == qt) {  // diagonal tile: causal mask
#pragma unroll
      for (int c = 0; c < 4; c++)
#pragma unroll
        for (int j = 0; j < 4; j++) {
          int qg = q0 + lg * 4 + j;
          int kg = qt * 64 + c * 16 + lr;
          if (kg > qg) sc[c][j] = -1e9f;
        }
    }

#pragma unroll
    for (int j = 0; j < 4; j++) {
      float mt = fmaxf(fmaxf(sc[0][j], sc[1][j]), fmaxf(sc[2][j], sc[3][j]));
#pragma unroll
      for (int d = 8; d >= 1; d >>= 1) mt = fmaxf(mt, __shfl_xor(mt, d));
      float mnew = fmaxf(mrun[j], mt);
      float corr = __expf(mrun[j] - mnew);
      float ps = 0.f;
#pragma unroll
      for (int c = 0; c < 4; c++) {
        float p = __expf(sc[c][j] - mnew);
        sc[c][j] = p;
        ps += p;
      }
#pragma unroll
      for (int d = 8; d >= 1; d >>= 1) ps += __shfl_xor(ps, d);
      lrun[j] = lrun[j] * corr + ps;
      mrun[j] = mnew;
#pragma unroll
      for (int n = 0; n < 4; n++) oacc[n][j] *= corr;
    }

    char* pw = (char*)Ps[wave];
#pragma unroll
    for (int c = 0; c < 4; c++)
#pragma unroll
      for (int j = 0; j < 4; j++) {
        int row = lg * 4 + j;
        *(u16*)(pw + row * 128 + ((((c * 16 + lr) * 2)) ^ ((row & 7) << 4))) = f2b(sc[c][j]);
      }

    {
      int smq = (lr & 7) << 4;
      bf16x8 pa0 = *(const bf16x8*)(pw + lr * 128 + ((lg * 16) ^ smq));
      bf16x8 pa1 = *(const bf16x8*)(pw + lr * 128 + ((64 + lg * 16) ^ smq));
      __builtin_amdgcn_s_setprio(1);
#pragma unroll
      for (int n = 0; n < 4; n++) {
        int row = n * 16 + lr;
        const char* vp = (const char*)Vs + row * 128;
        int sm = (row & 7) << 4;
        bf16x8 v0 = *(const bf16x8*)(vp + ((lg * 16) ^ sm));
        bf16x8 v1 = *(const bf16x8*)(vp + ((64 + lg * 16) ^ sm));
        oacc[n] = __builtin_amdgcn_mfma_f32_16x16x32_bf16(pa0, v0, oacc[n], 0, 0, 0);
        oacc[n] = __builtin_amdgcn_mfma_f32_16x16x32_bf16(pa1, v1, oacc[n], 0, 0, 0);
      }
      __builtin_amdgcn_s_setprio(0);
    }
    __syncthreads();
  }

#pragma unroll
  for (int j = 0; j < 4; j++) {
    float inv = 1.0f / lrun[j];
    int s_ = qt * 64 + wave * 16 + lg * 4 + j;
    size_t orow = ((size_t)b_ * NS + s_) * ND + h_ * NDH;
#pragma unroll
    for (int n = 0; n < 4; n++)
      O[orow + n * 16 + lr] = f2b(oacc[n][j] * inv);
  }
}

// ---------------- host launch ----------------
extern "C" void kernel_launch(void* const* d_in, const int* in_sizes, int n_in,
                              void* d_out, int out_size, void* d_ws, size_t ws_size,
                              hipStream_t stream) {
  const int* ids = (const int*)d_in[0];
  const float* tok_emb = (const float*)d_in[1];
  const float* Wq = (const float*)d_in[2];
  const float* bq = (const float*)d_in[3];
  const float* Wk = (const float*)d_in[4];
  const float* bk = (const float*)d_in[5];
  const float* Wv = (const float*)d_in[6];
  const float* bv = (const float*)d_in[7];
  const float* Wo = (const float*)d_in[8];
  const float* bo = (const float*)d_in[9];
  const float* ln1g = (const float*)d_in[10];
  const float* ln1b = (const float*)d_in[11];
  const float* W1 = (const float*)d_in[12];
  const float* b1 = (const float*)d_in[13];
  const float* W2 = (const float*)d_in[14];
  const float* b2 = (const float*)d_in[15];
  const float* ln3g = (const float*)d_in[16];
  const float* ln3b = (const float*)d_in[17];
  const float* Wout = (const float*)d_in[18];
  const float* bout = (const float*)d_in[19];
  float* out = (float*)d_out;

  char* ws = (char*)d_ws;
  size_t off = 0;
  auto alloc = [&](size_t bytes) -> void* {
    void* p = ws + off;
    off += (bytes + 255) & ~(size_t)255;
    return p;
  };
  float* x    = (float*)alloc((size_t)NM * ND * 4);
  float* tmp  = (float*)alloc((size_t)NM * ND * 4);
  u16* xb     = (u16*)alloc((size_t)NM * ND * 2);
  u16* hb     = (u16*)alloc((size_t)NM * NF * 2);
  u16* qkvb   = (u16*)alloc((size_t)3 * NM * ND * 2);   // Q,K:[B,H,S,DH]; V:[B,H,DH,S]
  u16* ob     = (u16*)alloc((size_t)NM * ND * 2);
  u16* Wqkvt  = (u16*)alloc((size_t)NL * 3 * ND * ND * 2); // [L][3072][1024]
  u16* Wot    = (u16*)alloc((size_t)NL * ND * ND * 2);
  u16* W1t    = (u16*)alloc((size_t)NL * (size_t)NF * ND * 2);
  u16* W2t    = (u16*)alloc((size_t)NL * (size_t)ND * NF * 2);
  u16* Woutt  = (u16*)alloc((size_t)NV * ND * 2);

  // ---- weight transpose+convert (every call; deterministic) ----
  for (int l = 0; l < NL; l++) {
    size_t wl = (size_t)l * ND * ND;
    u16* qkvl = Wqkvt + (size_t)l * 3 * ND * ND;
    dim3 gdd(ND / 32, ND / 32);
    k_transpose_convert<<<gdd, 256, 0, stream>>>(Wq + wl, qkvl, ND, ND);
    k_transpose_convert<<<gdd, 256, 0, stream>>>(Wk + wl, qkvl + (size_t)ND * ND, ND, ND);
    k_transpose_convert<<<gdd, 256, 0, stream>>>(Wv + wl, qkvl + (size_t)2 * ND * ND, ND, ND);
    k_transpose_convert<<<gdd, 256, 0, stream>>>(Wo + wl, Wot + wl, ND, ND);
    k_transpose_convert<<<dim3(NF / 32, ND / 32), 256, 0, stream>>>(
        W1 + (size_t)l * ND * NF, W1t + (size_t)l * (size_t)NF * ND, ND, NF);
    k_transpose_convert<<<dim3(ND / 32, NF / 32), 256, 0, stream>>>(
        W2 + (size_t)l * NF * ND, W2t + (size_t)l * (size_t)ND * NF, NF, ND);
  }
  k_transpose_convert<<<dim3(NV / 32, ND / 32), 256, 0, stream>>>(Wout, Woutt, ND, NV);

  // ---- embed + PE ----
  k_embed<<<NM, 256, 0, stream>>>(ids, tok_emb, x, xb);

  for (int l = 0; l < NL; l++) {
    size_t wl = (size_t)l * ND * ND;
    u16* qkvl = Wqkvt + (size_t)l * 3 * ND * ND;

    // fused QKV: [4096,1024] @ [1024,3072]; Q scaled 0.125; V stored transposed
    k_gemm_bt<3><<<dim3(NM / 128, 3 * ND / 128), 256, 0, stream>>>(
        xb, qkvl, bq + l * ND, bk + l * ND, bv + l * ND,
        nullptr, qkvb, NM, 3 * ND, ND, 0.125f);

    // flash attention
    k_attn<<<dim3(NS / 64, NB * NH), 256, 0, stream>>>(
        qkvb, qkvb + (size_t)NM * ND, qkvb + (size_t)2 * NM * ND, ob);

    // O projection (fp32 out)
    k_gemm_bt<0><<<dim3(NM / 128, ND / 128), 256, 0, stream>>>(
        ob, Wot + wl, bo + l * ND, nullptr, nullptr, tmp, nullptr, NM, ND, ND, 1.0f);

    // x = LN(x + attn_out)
    k_ln<<<NM, 256, 0, stream>>>(x, tmp, ln1g + l * ND, ln1b + l * ND, x, xb);

    // FFN1: relu, bf16 out
    k_gemm_bt<1><<<dim3(NM / 128, NF / 128), 256, 0, stream>>>(
        xb, W1t + (size_t)l * (size_t)NF * ND, b1 + l * NF, nullptr, nullptr,
        nullptr, hb, NM, NF, ND, 1.0f);

    // FFN2: fp32 out
    k_gemm_bt<0><<<dim3(NM / 128, ND / 128), 256, 0, stream>>>(
        hb, W2t + (size_t)l * (size_t)ND * NF, b2 + l * ND, nullptr, nullptr,
        tmp, nullptr, NM, ND, NF, 1.0f);

    // x = LN(x + ffn_out)
    k_ln<<<NM, 256, 0, stream>>>(x, tmp, ln3g + l * ND, ln3b + l * ND, x, xb);
  }

  // ---- logits: [4096,1024] @ [1024,32000] -> d_out fp32, M-fastest grid ----
  k_gemm_bt<0><<<dim3(NM / 128, NV / 128), 256, 0, stream>>>(
      xb, Woutt, bout, nullptr, nullptr, out, nullptr, NM, NV, ND, 1.0f);
}

// Round 6
// 1881.655 us; speedup vs baseline: 1.2930x; 1.0593x over previous
//
#include <hip/hip_runtime.h>
#include <stdint.h>

typedef unsigned short u16;
typedef __attribute__((ext_vector_type(8))) short bf16x8;
typedef __attribute__((ext_vector_type(4))) float f32x4;

#define NB 2
#define NS 2048
#define ND 1024
#define NH 16
#define NL 4
#define NV 32000
#define NF 4096
#define NDH 64
#define NM (NB*NS)   // 4096 token rows

__device__ __forceinline__ u16 f2b(float f) {
  union { float f; uint32_t u; } v; v.f = f;
  uint32_t r = v.u + 0x7FFFu + ((v.u >> 16) & 1u);
  return (u16)(r >> 16);
}

#define GLOAD_LDS16(gp, lp) __builtin_amdgcn_global_load_lds( \
    (const __attribute__((address_space(1))) void*)(gp), \
    (__attribute__((address_space(3))) void*)(lp), 16, 0, 0)

#define VMCNT8 do { asm volatile("s_waitcnt vmcnt(8)" ::: "memory"); __builtin_amdgcn_sched_barrier(0); } while (0)
#define VMCNT0 do { asm volatile("s_waitcnt vmcnt(0)" ::: "memory"); __builtin_amdgcn_sched_barrier(0); } while (0)
#define LGKM0  do { asm volatile("s_waitcnt lgkmcnt(0)" ::: "memory"); __builtin_amdgcn_sched_barrier(0); } while (0)

// ---------------- transpose + fp32->bf16 convert: w[K][N] -> wt[N][K] ----------------
__global__ __launch_bounds__(256)
void k_transpose_convert(const float* __restrict__ w, u16* __restrict__ wt, int K, int N) {
  __shared__ float tile[32][33];
  int n0 = blockIdx.x * 32;
  int k0 = blockIdx.y * 32;
  int tx = threadIdx.x & 31;
  int ty = threadIdx.x >> 5; // 0..7
#pragma unroll
  for (int i = 0; i < 4; i++) {
    int kk = ty + i * 8;
    tile[kk][tx] = w[(size_t)(k0 + kk) * N + (n0 + tx)];
  }
  __syncthreads();
#pragma unroll
  for (int i = 0; i < 4; i++) {
    int nn = ty + i * 8;
    wt[(size_t)(n0 + nn) * K + (k0 + tx)] = f2b(tile[tx][nn]);
  }
}

// ---------------- embedding + sinusoidal PE ----------------
__global__ __launch_bounds__(256)
void k_embed(const int* __restrict__ ids, const float* __restrict__ emb,
             float* __restrict__ x, u16* __restrict__ xb) {
  int row = blockIdx.x;          // b*NS + s
  int s = row & (NS - 1);
  int tok = ids[row];
  const float* e = emb + (size_t)tok * ND;
  int d0 = threadIdx.x * 4;
  float y[4];
#pragma unroll
  for (int j = 0; j < 4; j++) {
    int dd = d0 + j;
    float di = (float)(dd & ~1);
    float dv = expf(di * (-9.210340371976184f / (float)ND));
    float ang = (float)s * dv;
    float pe = (dd & 1) ? cosf(ang) : sinf(ang);
    y[j] = e[dd] * 32.0f + pe;
  }
  float4 w; w.x = y[0]; w.y = y[1]; w.z = y[2]; w.w = y[3];
  *(float4*)(x + (size_t)row * ND + d0) = w;
  uint2 pk;
  pk.x = (uint32_t)f2b(y[0]) | ((uint32_t)f2b(y[1]) << 16);
  pk.y = (uint32_t)f2b(y[2]) | ((uint32_t)f2b(y[3]) << 16);
  *(uint2*)(xb + (size_t)row * ND + d0) = pk;
}

// ---------------- fused residual add + LayerNorm ----------------
__global__ __launch_bounds__(256)
void k_ln(const float* __restrict__ xin, const float* __restrict__ add,
          const float* __restrict__ g, const float* __restrict__ bb,
          float* __restrict__ xout, u16* __restrict__ xbout) {
  int row = blockIdx.x;
  int t = threadIdx.x;
  const float4 xi = *(const float4*)(xin + (size_t)row * ND + t * 4);
  const float4 ai = *(const float4*)(add + (size_t)row * ND + t * 4);
  float v0 = xi.x + ai.x, v1 = xi.y + ai.y, v2 = xi.z + ai.z, v3 = xi.w + ai.w;
  float s = v0 + v1 + v2 + v3;
  float s2 = v0 * v0 + v1 * v1 + v2 * v2 + v3 * v3;
#pragma unroll
  for (int d = 32; d >= 1; d >>= 1) { s += __shfl_xor(s, d); s2 += __shfl_xor(s2, d); }
  __shared__ float rs[8];
  int w = t >> 6;
  if ((t & 63) == 0) { rs[w] = s; rs[4 + w] = s2; }
  __syncthreads();
  s = rs[0] + rs[1] + rs[2] + rs[3];
  s2 = rs[4] + rs[5] + rs[6] + rs[7];
  float mu = s * (1.0f / ND);
  float var = s2 * (1.0f / ND) - mu * mu;
  float rr = rsqrtf(var + 1e-5f);
  const float4 gg = *(const float4*)(g + t * 4);
  const float4 be = *(const float4*)(bb + t * 4);
  float y0 = (v0 - mu) * rr * gg.x + be.x;
  float y1 = (v1 - mu) * rr * gg.y + be.y;
  float y2 = (v2 - mu) * rr * gg.z + be.z;
  float y3 = (v3 - mu) * rr * gg.w + be.w;
  float4 yo; yo.x = y0; yo.y = y1; yo.z = y2; yo.w = y3;
  *(float4*)(xout + (size_t)row * ND + t * 4) = yo;
  uint2 pk;
  pk.x = (uint32_t)f2b(y0) | ((uint32_t)f2b(y1) << 16);
  pk.y = (uint32_t)f2b(y2) | ((uint32_t)f2b(y3) << 16);
  *(uint2*)(xbout + (size_t)row * ND + t * 4) = pk;
}

// ---------------- 128x128 bf16 MFMA GEMM (m97 structure) ----------------
// MODE 0: fp32 store to Cf
// MODE 1: relu, bf16 store to Cb
// MODE 3: fused QKV: N=3072, scale q; Q,K -> [B,H,S,DH]; V -> [B,H,DH,S] (transposed)
template<int MODE>
__global__ __launch_bounds__(256)
void k_gemm_bt(const u16* __restrict__ A, const u16* __restrict__ Bt,
               const float* __restrict__ bias0, const float* __restrict__ bias1,
               const float* __restrict__ bias2,
               float* __restrict__ Cf, u16* __restrict__ Cb,
               int M, int N, int K, float scale) {
  constexpr int BM = 128, BN = 128, BK = 32;
  __shared__ __align__(16) u16 As[2][BM * BK];
  __shared__ __align__(16) u16 Bs[2][BN * BK];

  const int tid = threadIdx.x;
  const int lane = tid & 63;
  const int wave = tid >> 6;

  const int bm = blockIdx.x * BM;
  const int bn = blockIdx.y * BN;

  const int wr = (wave >> 1) * 64;
  const int wc = (wave & 1) * 64;
  const int lr = lane & 15;
  const int lk = (lane >> 4) * 8;

  const u16* Abase = A + (size_t)bm * K;
  const u16* Bbase = Bt + (size_t)bn * K;
  const int srow = lane >> 2;        // 0..15
  const int scol = (lane & 3) * 8;   // u16 col within BK

  auto stage = [&](int buf, int kt) {
    const u16* Ag = Abase + (size_t)kt * BK + scol;
    const u16* Bg = Bbase + (size_t)kt * BK + scol;
#pragma unroll
    for (int i = 0; i < 2; i++) {
      const int rbase = (i * 4 + wave) * 16;       // first row of this 1KB chunk
      GLOAD_LDS16(Ag + (size_t)(rbase + srow) * K, &As[buf][rbase * BK]);
      GLOAD_LDS16(Bg + (size_t)(rbase + srow) * K, &Bs[buf][rbase * BK]);
    }
  };

  f32x4 acc[4][4] = {};
  const int nk = K / BK;
  stage(0, 0);
  for (int kt = 0; kt < nk; ++kt) {
    __syncthreads();                       // drains vmcnt -> buf[kt&1] ready
    if (kt + 1 < nk) stage((kt + 1) & 1, kt + 1);
    const int buf = kt & 1;
    bf16x8 af[4], bfv[4];
#pragma unroll
    for (int m = 0; m < 4; m++)
      af[m] = *(const bf16x8*)(&As[buf][(wr + m * 16 + lr) * BK + lk]);
#pragma unroll
    for (int n = 0; n < 4; n++)
      bfv[n] = *(const bf16x8*)(&Bs[buf][(wc + n * 16 + lr) * BK + lk]);
#pragma unroll
    for (int m = 0; m < 4; m++)
#pragma unroll
      for (int n = 0; n < 4; n++)
        acc[m][n] = __builtin_amdgcn_mfma_f32_16x16x32_bf16(af[m], bfv[n], acc[m][n], 0, 0, 0);
  }

  const int lg = lane >> 4;
#pragma unroll
  for (int m = 0; m < 4; m++) {
#pragma unroll
    for (int n = 0; n < 4; n++) {
      int col = bn + wc + n * 16 + lr;
      float bv;
      if (MODE == 3) {
        int which = col >> 10;
        int cc = col & 1023;
        const float* bp = (which == 0) ? bias0 : ((which == 1) ? bias1 : bias2);
        bv = bp[cc];
      } else {
        bv = bias0[col];
      }
      if (MODE == 3 && (col >> 10) == 2) {
        // V: packed transposed store -> [B,H,DH,S]
        int cc = col & 1023;
        int row0 = bm + wr + m * 16 + lg * 4;
        int b_ = row0 >> 11;
        int s_ = row0 & (NS - 1);
        int h_ = cc >> 6;
        int dh = cc & 63;
        ushort4 pk;
        pk.x = f2b(acc[m][n][0] + bv);
        pk.y = f2b(acc[m][n][1] + bv);
        pk.z = f2b(acc[m][n][2] + bv);
        pk.w = f2b(acc[m][n][3] + bv);
        *(ushort4*)(Cb + (size_t)2 * NM * ND +
                    ((((size_t)b_ * NH + h_) * NDH) + dh) * NS + s_) = pk;
        continue;
      }
#pragma unroll
      for (int j = 0; j < 4; j++) {
        int row = bm + wr + m * 16 + lg * 4 + j;
        float v = acc[m][n][j] + bv;
        if (MODE == 0) {
          Cf[(size_t)row * N + col] = v;
        } else if (MODE == 1) {
          Cb[(size_t)row * N + col] = f2b(fmaxf(v, 0.0f));
        } else { // MODE 3: Q/K permuted store -> [B,H,S,DH]
          int which = col >> 10;
          int cc = col & 1023;
          if (which == 0) v *= scale;
          int b_ = row >> 11;          // /NS
          int s_ = row & (NS - 1);
          int h_ = cc >> 6;
          int dh = cc & 63;
          Cb[(size_t)which * ((size_t)NM * ND) +
             ((((size_t)b_ * NH + h_) * NS) + s_) * NDH + dh] = f2b(v);
        }
      }
    }
  }
}

// ---------------- 256x256 BK=64 8-wave deep-pipelined bf16 GEMM ----------------
// Counted-vmcnt schedule (raw s_barrier, never vmcnt(0) in main loop), XOR-swizzled
// LDS reads with inverse-swizzled global_load_lds sources (rule #21), setprio on
// MFMA clusters. MODE 0: fp32+bias. MODE 1: relu -> bf16.
template<int MODE>
__global__ __launch_bounds__(512, 2)
void k_gemm256(const u16* __restrict__ A, const u16* __restrict__ Bt,
               const float* __restrict__ bias,
               float* __restrict__ Cf, u16* __restrict__ Cb,
               int M, int N, int K) {
  __shared__ __align__(16) u16 As2[2][256 * 64];   // 64 KB
  __shared__ __align__(16) u16 Bs2[2][256 * 64];   // 64 KB

  const int tid = threadIdx.x;
  const int lane = tid & 63;
  const int wave = tid >> 6;          // 0..7
  const int wrM = wave >> 2;          // 0..1 -> M offset *128
  const int wcN = wave & 3;           // 0..3 -> N offset *64
  const int lr = lane & 15;
  const int g = lane >> 4;            // 0..3
  const int r7 = lr & 7;

  const int bm = blockIdx.x * 256;
  const int bn = blockIdx.y * 256;

  // staging geometry: per instr s (0..3), wave covers rows [(s*8+wave)*8, +8)
  const int srow_in = lane >> 3;          // 0..7 within 8-row chunk
  const int schunk = lane & 7;            // 16B chunk within 128B row
  const int sq = (schunk ^ srow_in) * 8;  // inverse-swizzled global u16 col offset

  auto stageT = [&](int buf, int t) {
#pragma unroll
    for (int s = 0; s < 4; ++s) {
      const int rbase = (s * 8 + wave) * 8;
      const int row = rbase + srow_in;
      GLOAD_LDS16(A + (size_t)(bm + row) * K + t * 64 + sq, &As2[buf][rbase * 64]);
      GLOAD_LDS16(Bt + (size_t)(bn + row) * K + t * 64 + sq, &Bs2[buf][rbase * 64]);
    }
  };

  f32x4 acc[8][4] = {};
  const int NT = K / 64;

  stageT(0, 0);
  stageT(1, 1);

  for (int t = 0; t < NT; ++t) {
    const int buf = t & 1;
    if (t == NT - 1) { VMCNT0; } else { VMCNT8; }
    __builtin_amdgcn_s_barrier();   // all waves' tile-t stages landed

    const char* ab = (const char*)(&As2[buf][0]);
    const char* bb = (const char*)(&Bs2[buf][0]);
    bf16x8 aF[8], bF[4];
    // kk = 0 fragments (chunk = g, swizzled ^= row&7 = r7)
#pragma unroll
    for (int n = 0; n < 4; n++) {
      int row = wcN * 64 + n * 16 + lr;
      bF[n] = *(const bf16x8*)(bb + row * 128 + ((g ^ r7) * 16));
    }
#pragma unroll
    for (int m = 0; m < 8; m++) {
      int row = wrM * 128 + m * 16 + lr;
      aF[m] = *(const bf16x8*)(ab + row * 128 + ((g ^ r7) * 16));
    }
    __builtin_amdgcn_s_setprio(1);
#pragma unroll
    for (int m = 0; m < 8; m++)
#pragma unroll
      for (int n = 0; n < 4; n++)
        acc[m][n] = __builtin_amdgcn_mfma_f32_16x16x32_bf16(aF[m], bF[n], acc[m][n], 0, 0, 0);
    __builtin_amdgcn_s_setprio(0);

    // kk = 1 fragments (chunk = 4+g)
    bf16x8 aG[8], bG[4];
#pragma unroll
    for (int n = 0; n < 4; n++) {
      int row = wcN * 64 + n * 16 + lr;
      bG[n] = *(const bf16x8*)(bb + row * 128 + (((4 + g) ^ r7) * 16));
    }
#pragma unroll
    for (int m = 0; m < 8; m++) {
      int row = wrM * 128 + m * 16 + lr;
      aG[m] = *(const bf16x8*)(ab + row * 128 + (((4 + g) ^ r7) * 16));
    }
    LGKM0;                          // my LDS reads complete
    __builtin_amdgcn_s_barrier();   // all waves done reading buf -> safe to overwrite
    if (t + 2 < NT) stageT(buf, t + 2);
    __builtin_amdgcn_s_setprio(1);
#pragma unroll
    for (int m = 0; m < 8; m++)
#pragma unroll
      for (int n = 0; n < 4; n++)
        acc[m][n] = __builtin_amdgcn_mfma_f32_16x16x32_bf16(aG[m], bG[n], acc[m][n], 0, 0, 0);
    __builtin_amdgcn_s_setprio(0);
  }

  // epilogue
#pragma unroll
  for (int m = 0; m < 8; m++) {
#pragma unroll
    for (int n = 0; n < 4; n++) {
      int col = bn + wcN * 64 + n * 16 + lr;
      float bv = bias[col];
#pragma unroll
      for (int j = 0; j < 4; j++) {
        int row = bm + wrM * 128 + m * 16 + g * 4 + j;
        float v = acc[m][n][j] + bv;
        if (MODE == 0) Cf[(size_t)row * N + col] = v;
        else           Cb[(size_t)row * N + col] = f2b(fmaxf(v, 0.0f));
      }
    }
  }
}

// ---------------- flash attention (causal), Q pre-scaled by 1/sqrt(DH) ----------------
__global__ __launch_bounds__(256)
void k_attn(const u16* __restrict__ Q, const u16* __restrict__ Kq,
            const u16* __restrict__ Vt, u16* __restrict__ O) {
  const int qt = blockIdx.x;   // q tile of 64 rows
  const int bh = blockIdx.y;   // b*NH + h
  const int b_ = bh >> 4, h_ = bh & 15;
  const int tid = threadIdx.x, lane = tid & 63, wave = tid >> 6;
  const int lr = lane & 15, lg = lane >> 4;

  __shared__ __align__(16) u16 Ks[64 * 64];      // [key][dh] swizzled
  __shared__ __align__(16) u16 Vs[64 * 64];      // [dh][key] swizzled
  __shared__ __align__(16) u16 Ps[4][16 * 64];   // per-wave P [qrow][key] swizzled

  const size_t base = (size_t)bh * NS * NDH;     // same for [B,H,S,DH] and [B,H,DH,S]
  bf16x8 qf0, qf1;
  {
    const u16* qp = Q + base + (size_t)(qt * 64 + wave * 16 + lr) * NDH;
    qf0 = *(const bf16x8*)(qp + lg * 8);
    qf1 = *(const bf16x8*)(qp + 32 + lg * 8);
  }

  const int idx0 = tid, idx1 = tid + 256;
  const int r0 = idx0 >> 3, r1 = idx1 >> 3;
  const int c0 = (idx0 & 7) * 8, c1 = (idx1 & 7) * 8;
  const int so0 = r0 * 128 + ((c0 * 2) ^ ((r0 & 7) << 4));
  const int so1 = r1 * 128 + ((c1 * 2) ^ ((r1 & 7) << 4));

  bf16x8 rk0, rk1, rv0, rv1;   // T14 prefetch registers
  auto loadregs = [&](int kt2) {
    const u16* Kg = Kq + base + (size_t)(kt2 * 64) * NDH;
    const u16* Vg = Vt + base + kt2 * 64;
    rk0 = *(const bf16x8*)(Kg + (size_t)r0 * NDH + c0);
    rk1 = *(const bf16x8*)(Kg + (size_t)r1 * NDH + c1);
    rv0 = *(const bf16x8*)(Vg + (size_t)r0 * NS + c0);
    rv1 = *(const bf16x8*)(Vg + (size_t)r1 * NS + c1);
  };

  float mrun[4] = {-1e30f, -1e30f, -1e30f, -1e30f};
  float lrun[4] = {0.f, 0.f, 0.f, 0.f};
  f32x4 oacc[4] = {};
  const int q0 = qt * 64 + wave * 16;

  loadregs(0);
  for (int kt2 = 0; kt2 <= qt; ++kt2) {
    *(bf16x8*)((char*)Ks + so0) = rk0;
    *(bf16x8*)((char*)Ks + so1) = rk1;
    *(bf16x8*)((char*)Vs + so0) = rv0;
    *(bf16x8*)((char*)Vs + so1) = rv1;
    __syncthreads();
    if (kt2 < qt) loadregs(kt2 + 1);

    f32x4 sc[4];
    __builtin_amdgcn_s_setprio(1);
#pragma unroll
    for (int c = 0; c < 4; c++) {
      int row = c * 16 + lr;
      const char* kp = (const char*)Ks + row * 128;
      int sm = (row & 7) << 4;
      bf16x8 k0 = *(const bf16x8*)(kp + ((lg * 16) ^ sm));
      bf16x8 k1 = *(const bf16x8*)(kp + ((64 + lg * 16) ^ sm));
      f32x4 s = {};
      s = __builtin_amdgcn_mfma_f32_16x16x32_bf16(qf0, k0, s, 0, 0, 0);
      s = __builtin_amdgcn_mfma_f32_16x16x32_bf16(qf1, k1, s, 0, 0, 0);
      sc[c] = s;
    }
    __builtin_amdgcn_s_setprio(0);

    if (kt2 == qt) {
#pragma unroll
      for (int c = 0; c < 4; c++)
#pragma unroll
        for (int j = 0; j < 4; j++) {
          int qg = q0 + lg * 4 + j;
          int kg = qt * 64 + c * 16 + lr;
          if (kg > qg) sc[c][j] = -1e9f;
        }
    }

#pragma unroll
    for (int j = 0; j < 4; j++) {
      float mt = fmaxf(fmaxf(sc[0][j], sc[1][j]), fmaxf(sc[2][j], sc[3][j]));
#pragma unroll
      for (int d = 8; d >= 1; d >>= 1) mt = fmaxf(mt, __shfl_xor(mt, d));
      float mnew = fmaxf(mrun[j], mt);
      float corr = __expf(mrun[j] - mnew);
      float ps = 0.f;
#pragma unroll
      for (int c = 0; c < 4; c++) {
        float p = __expf(sc[c][j] - mnew);
        sc[c][j] = p;
        ps += p;
      }
#pragma unroll
      for (int d = 8; d >= 1; d >>= 1) ps += __shfl_xor(ps, d);
      lrun[j] = lrun[j] * corr + ps;
      mrun[j] = mnew;
#pragma unroll
      for (int n = 0; n < 4; n++) oacc[n][j] *= corr;
    }

    char* pw = (char*)Ps[wave];
#pragma unroll
    for (int c = 0; c < 4; c++)
#pragma unroll
      for (int j = 0; j < 4; j++) {
        int row = lg * 4 + j;
        *(u16*)(pw + row * 128 + ((((c * 16 + lr) * 2)) ^ ((row & 7) << 4))) = f2b(sc[c][j]);
      }

    {
      int smq = (lr & 7) << 4;
      bf16x8 pa0 = *(const bf16x8*)(pw + lr * 128 + ((lg * 16) ^ smq));
      bf16x8 pa1 = *(const bf16x8*)(pw + lr * 128 + ((64 + lg * 16) ^ smq));
      __builtin_amdgcn_s_setprio(1);
#pragma unroll
      for (int n = 0; n < 4; n++) {
        int row = n * 16 + lr;
        const char* vp = (const char*)Vs + row * 128;
        int sm = (row & 7) << 4;
        bf16x8 v0 = *(const bf16x8*)(vp + ((lg * 16) ^ sm));
        bf16x8 v1 = *(const bf16x8*)(vp + ((64 + lg * 16) ^ sm));
        oacc[n] = __builtin_amdgcn_mfma_f32_16x16x32_bf16(pa0, v0, oacc[n], 0, 0, 0);
        oacc[n] = __builtin_amdgcn_mfma_f32_16x16x32_bf16(pa1, v1, oacc[n], 0, 0, 0);
      }
      __builtin_amdgcn_s_setprio(0);
    }
    __syncthreads();
  }

#pragma unroll
  for (int j = 0; j < 4; j++) {
    float inv = 1.0f / lrun[j];
    int s_ = qt * 64 + wave * 16 + lg * 4 + j;
    size_t orow = ((size_t)b_ * NS + s_) * ND + h_ * NDH;
#pragma unroll
    for (int n = 0; n < 4; n++)
      O[orow + n * 16 + lr] = f2b(oacc[n][j] * inv);
  }
}

// ---------------- host launch ----------------
extern "C" void kernel_launch(void* const* d_in, const int* in_sizes, int n_in,
                              void* d_out, int out_size, void* d_ws, size_t ws_size,
                              hipStream_t stream) {
  const int* ids = (const int*)d_in[0];
  const float* tok_emb = (const float*)d_in[1];
  const float* Wq = (const float*)d_in[2];
  const float* bq = (const float*)d_in[3];
  const float* Wk = (const float*)d_in[4];
  const float* bk = (const float*)d_in[5];
  const float* Wv = (const float*)d_in[6];
  const float* bv = (const float*)d_in[7];
  const float* Wo = (const float*)d_in[8];
  const float* bo = (const float*)d_in[9];
  const float* ln1g = (const float*)d_in[10];
  const float* ln1b = (const float*)d_in[11];
  const float* W1 = (const float*)d_in[12];
  const float* b1 = (const float*)d_in[13];
  const float* W2 = (const float*)d_in[14];
  const float* b2 = (const float*)d_in[15];
  const float* ln3g = (const float*)d_in[16];
  const float* ln3b = (const float*)d_in[17];
  const float* Wout = (const float*)d_in[18];
  const float* bout = (const float*)d_in[19];
  float* out = (float*)d_out;

  char* ws = (char*)d_ws;
  size_t off = 0;
  auto alloc = [&](size_t bytes) -> void* {
    void* p = ws + off;
    off += (bytes + 255) & ~(size_t)255;
    return p;
  };
  float* x    = (float*)alloc((size_t)NM * ND * 4);
  float* tmp  = (float*)alloc((size_t)NM * ND * 4);
  u16* xb     = (u16*)alloc((size_t)NM * ND * 2);
  u16* hb     = (u16*)alloc((size_t)NM * NF * 2);
  u16* qkvb   = (u16*)alloc((size_t)3 * NM * ND * 2);   // Q,K:[B,H,S,DH]; V:[B,H,DH,S]
  u16* ob     = (u16*)alloc((size_t)NM * ND * 2);
  u16* Wqkvt  = (u16*)alloc((size_t)NL * 3 * ND * ND * 2); // [L][3072][1024]
  u16* Wot    = (u16*)alloc((size_t)NL * ND * ND * 2);
  u16* W1t    = (u16*)alloc((size_t)NL * (size_t)NF * ND * 2);
  u16* W2t    = (u16*)alloc((size_t)NL * (size_t)ND * NF * 2);
  u16* Woutt  = (u16*)alloc((size_t)NV * ND * 2);

  // ---- weight transpose+convert (every call; deterministic) ----
  for (int l = 0; l < NL; l++) {
    size_t wl = (size_t)l * ND * ND;
    u16* qkvl = Wqkvt + (size_t)l * 3 * ND * ND;
    dim3 gdd(ND / 32, ND / 32);
    k_transpose_convert<<<gdd, 256, 0, stream>>>(Wq + wl, qkvl, ND, ND);
    k_transpose_convert<<<gdd, 256, 0, stream>>>(Wk + wl, qkvl + (size_t)ND * ND, ND, ND);
    k_transpose_convert<<<gdd, 256, 0, stream>>>(Wv + wl, qkvl + (size_t)2 * ND * ND, ND, ND);
    k_transpose_convert<<<gdd, 256, 0, stream>>>(Wo + wl, Wot + wl, ND, ND);
    k_transpose_convert<<<dim3(NF / 32, ND / 32), 256, 0, stream>>>(
        W1 + (size_t)l * ND * NF, W1t + (size_t)l * (size_t)NF * ND, ND, NF);
    k_transpose_convert<<<dim3(ND / 32, NF / 32), 256, 0, stream>>>(
        W2 + (size_t)l * NF * ND, W2t + (size_t)l * (size_t)ND * NF, NF, ND);
  }
  k_transpose_convert<<<dim3(NV / 32, ND / 32), 256, 0, stream>>>(Wout, Woutt, ND, NV);

  // ---- embed + PE ----
  k_embed<<<NM, 256, 0, stream>>>(ids, tok_emb, x, xb);

  for (int l = 0; l < NL; l++) {
    size_t wl = (size_t)l * ND * ND;
    u16* qkvl = Wqkvt + (size_t)l * 3 * ND * ND;

    // fused QKV: [4096,1024] @ [1024,3072]; Q scaled 0.125; V stored transposed
    k_gemm_bt<3><<<dim3(NM / 128, 3 * ND / 128), 256, 0, stream>>>(
        xb, qkvl, bq + l * ND, bk + l * ND, bv + l * ND,
        nullptr, qkvb, NM, 3 * ND, ND, 0.125f);

    // flash attention
    k_attn<<<dim3(NS / 64, NB * NH), 256, 0, stream>>>(
        qkvb, qkvb + (size_t)NM * ND, qkvb + (size_t)2 * NM * ND, ob);

    // O projection (fp32 out)
    k_gemm_bt<0><<<dim3(NM / 128, ND / 128), 256, 0, stream>>>(
        ob, Wot + wl, bo + l * ND, nullptr, nullptr, tmp, nullptr, NM, ND, ND, 1.0f);

    // x = LN(x + attn_out)
    k_ln<<<NM, 256, 0, stream>>>(x, tmp, ln1g + l * ND, ln1b + l * ND, x, xb);

    // FFN1: relu, bf16 out — 256² deep-pipelined
    k_gemm256<1><<<dim3(NM / 256, NF / 256), 512, 0, stream>>>(
        xb, W1t + (size_t)l * (size_t)NF * ND, b1 + l * NF, nullptr, hb, NM, NF, ND);

    // FFN2: fp32 out
    k_gemm_bt<0><<<dim3(NM / 128, ND / 128), 256, 0, stream>>>(
        hb, W2t + (size_t)l * (size_t)ND * NF, b2 + l * ND, nullptr, nullptr,
        tmp, nullptr, NM, ND, NF, 1.0f);

    // x = LN(x + ffn_out)
    k_ln<<<NM, 256, 0, stream>>>(x, tmp, ln3g + l * ND, ln3b + l * ND, x, xb);
  }

  // ---- logits: [4096,1024] @ [1024,32000] -> d_out fp32 — 256² deep-pipelined ----
  k_gemm256<0><<<dim3(NM / 256, NV / 256), 512, 0, stream>>>(
      xb, Woutt, bout, out, nullptr, NM, NV, ND);
}